// Round 4
// baseline (1077.861 us; speedup 1.0000x reference)
//
#include <hip/hip_runtime.h>

// ---------------------------------------------------------------------------
// AttentionBlock: GroupNorm(32) -> q,k,v = xn@W+b -> softmax(q k^T / sqrt(C)) v
//                 -> out@wp+bp + x.   B=2, H=W=64, C=512, S=4096 per batch.
// Round 4: attn was L2-BW-bound on redundant K/V streams (8 MB/XCD/step).
//   - Q-tile 32 -> 128 rows/block (1024 thr, 16 waves = 8 rowgroups x 2
//     channel halves): K/V traffic per Q-row cut 4x -> 3 MB/XCD/step.
//   - split-K x4 -> 256 blocks = 1/CU, 16 waves/CU (VGPR pool exactly full
//     at 128 VGPR x 4 waves/SIMD).
//   - XCD swizzle: xcd == (batch,split) -> each XCD streams one 2 MB K/V
//     slice resident in its private L2.
//   - combine kernel merges 4 partials.
// ---------------------------------------------------------------------------

typedef __bf16 bf16_t;
typedef __bf16 bf16x8 __attribute__((ext_vector_type(8)));
typedef __bf16 bf16x4 __attribute__((ext_vector_type(4)));
typedef float  f32x4  __attribute__((ext_vector_type(4)));

__device__ __forceinline__ bf16x8 ld8(const bf16_t* p) {
    return *reinterpret_cast<const bf16x8*>(p);
}
__device__ __forceinline__ f32x4 mfma16(bf16x8 a, bf16x8 b, f32x4 c) {
    return __builtin_amdgcn_mfma_f32_16x16x32_bf16(a, b, c, 0, 0, 0);
}
__device__ __forceinline__ void gload16(const bf16_t* gp, bf16_t* lp) {
    // HW semantics: LDS dest = uniform base + laneid*16B; gp is per-lane.
    __builtin_amdgcn_global_load_lds(
        (const __attribute__((address_space(1))) void*)gp,
        (__attribute__((address_space(3))) void*)lp, 16, 0, 0);
}

#define NPIX 8192      // B*H*W
#define C512 512
#define SEQ  4096      // H*W per batch
#define QSCALE 0.044194173824159216f   // 512^-0.5
#define NSPLIT 4
#define KTILES 32      // 32-key tiles per split (1024 keys per split)

// ---------------- GroupNorm stats: one block per (b,g), 64 blocks -----------
__global__ __launch_bounds__(256) void gn_stats_k(const float* __restrict__ x,
                                                  float* __restrict__ stats) {
    int bg = blockIdx.x;               // b*32+g
    int b  = bg >> 5, g = bg & 31;
    const float* xp = x + (size_t)b * SEQ * C512 + g * 16;
    float s = 0.f, s2 = 0.f;
    for (int p = threadIdx.x; p < SEQ; p += 256) {
        const float4* q = reinterpret_cast<const float4*>(xp + (size_t)p * C512);
        #pragma unroll
        for (int i = 0; i < 4; i++) {
            float4 v = q[i];
            s  += v.x + v.y + v.z + v.w;
            s2 += v.x*v.x + v.y*v.y + v.z*v.z + v.w*v.w;
        }
    }
    #pragma unroll
    for (int off = 32; off >= 1; off >>= 1) {
        s  += __shfl_down(s, off);
        s2 += __shfl_down(s2, off);
    }
    __shared__ float rs[4], rs2[4];
    int wave = threadIdx.x >> 6;
    if ((threadIdx.x & 63) == 0) { rs[wave] = s; rs2[wave] = s2; }
    __syncthreads();
    if (threadIdx.x == 0) {
        float S = 0.f, S2 = 0.f;
        for (int i = 0; i < 4; i++) { S += rs[i]; S2 += rs2[i]; }
        float mean = S * (1.f / 65536.f);
        float var  = S2 * (1.f / 65536.f) - mean * mean;
        stats[bg * 2]     = mean;
        stats[bg * 2 + 1] = rsqrtf(var + 1e-5f);
    }
}

// ---------------- weights: fp32 (k,n) -> bf16 transposed (n,k) --------------
// y=0..2 -> wqkvT rows [y*512, y*512+512); y=0 (wq) folded with QSCALE.
// y=3 -> wpT.
__global__ __launch_bounds__(256) void wt_conv_k(const float* wq, const float* wk,
                                                 const float* wv, const float* wp,
                                                 bf16_t* wqkvT, bf16_t* wpT) {
    int y = blockIdx.y;
    const float* w = (y == 0) ? wq : (y == 1) ? wk : (y == 2) ? wv : wp;
    float scale = (y == 0) ? QSCALE : 1.0f;
    int tid = blockIdx.x * 256 + threadIdx.x;     // 262144 total
    int n = tid >> 9, k = tid & 511;
    bf16_t val = (bf16_t)(w[(size_t)k * C512 + n] * scale);
    if (y < 3) wqkvT[((size_t)y * C512 + n) * C512 + k] = val;
    else       wpT[(size_t)n * C512 + k] = val;
}

// ---------------- xn = groupnorm(x)*gamma+beta -> bf16 ----------------------
__global__ __launch_bounds__(256) void xn_k(const float* __restrict__ x,
                                            const float* __restrict__ stats,
                                            const float* __restrict__ gamma,
                                            const float* __restrict__ beta,
                                            bf16_t* __restrict__ xn) {
    size_t idx = ((size_t)blockIdx.x * 256 + threadIdx.x) * 4;   // elem index
    int c = (int)(idx & 511);
    size_t pix = idx >> 9;
    int b = (int)(pix >> 12);
    int g = c >> 4;
    float mean = stats[(b * 32 + g) * 2];
    float rstd = stats[(b * 32 + g) * 2 + 1];
    float4 v  = *reinterpret_cast<const float4*>(x + idx);
    float4 gm = *reinterpret_cast<const float4*>(gamma + c);
    float4 bt = *reinterpret_cast<const float4*>(beta + c);
    bf16x4 o;
    o[0] = (bf16_t)((v.x - mean) * rstd * gm.x + bt.x);
    o[1] = (bf16_t)((v.y - mean) * rstd * gm.y + bt.y);
    o[2] = (bf16_t)((v.z - mean) * rstd * gm.z + bt.z);
    o[3] = (bf16_t)((v.w - mean) * rstd * gm.w + bt.w);
    *reinterpret_cast<bf16x4*>(xn + idx) = o;
}

// ---------------- fused QKV GEMM: D(8192,1536) = xn x wqkvT^T + bias --------
__global__ __launch_bounds__(256) void gemm_qkv_k(const bf16_t* __restrict__ A,
                                                  const bf16_t* __restrict__ WT,
                                                  const float* __restrict__ bq,
                                                  const float* __restrict__ bk,
                                                  const float* __restrict__ bv,
                                                  bf16_t* __restrict__ Qb,
                                                  bf16_t* __restrict__ Kb,
                                                  bf16_t* __restrict__ VTb) {
    int lane = threadIdx.x & 63;
    int w    = threadIdx.x >> 6;          // 4 waves, 2x2
    int lrow = lane & 15, quad = lane >> 4;
    int mbase = blockIdx.x * 64 + (w & 1) * 32;
    int nbase = blockIdx.y * 64 + (w >> 1) * 32;

    f32x4 acc[2][2] = {};
    const bf16_t* a0p = A  + (size_t)(mbase + lrow) * C512 + quad * 8;
    const bf16_t* a1p = a0p + 16 * C512;
    const bf16_t* b0p = WT + (size_t)(nbase + lrow) * C512 + quad * 8;
    const bf16_t* b1p = b0p + 16 * C512;

    #pragma unroll 4
    for (int kk = 0; kk < 16; kk++) {
        bf16x8 a0 = ld8(a0p + kk * 32);
        bf16x8 a1 = ld8(a1p + kk * 32);
        bf16x8 b0 = ld8(b0p + kk * 32);
        bf16x8 b1 = ld8(b1p + kk * 32);
        acc[0][0] = mfma16(a0, b0, acc[0][0]);
        acc[0][1] = mfma16(a0, b1, acc[0][1]);
        acc[1][0] = mfma16(a1, b0, acc[1][0]);
        acc[1][1] = mfma16(a1, b1, acc[1][1]);
    }

    #pragma unroll
    for (int mi = 0; mi < 2; mi++) {
        #pragma unroll
        for (int ni = 0; ni < 2; ni++) {
            int colG = nbase + ni * 16 + lrow;
            int seg = colG >> 9, col = colG & 511;
            const float* bias = (seg == 0) ? bq : (seg == 1) ? bk : bv;
            float bvv = bias[col] * ((seg == 0) ? QSCALE : 1.0f);
            int rowb = mbase + mi * 16 + quad * 4;
            #pragma unroll
            for (int i = 0; i < 4; i++) {
                int row = rowb + i;
                bf16_t val = (bf16_t)(acc[mi][ni][i] + bvv);
                if (seg == 0) {
                    Qb[(size_t)row * C512 + col] = val;
                } else if (seg == 1) {
                    Kb[(size_t)row * C512 + col] = val;
                } else {
                    int b = row >> 12, s = row & 4095;
                    VTb[((size_t)(b * C512 + col)) * SEQ + s] = val;
                }
            }
        }
    }
}

// ---------------- out-projection GEMM + residual ----------------------------
__global__ __launch_bounds__(256) void gemm_out_k(const bf16_t* __restrict__ A,
                                                  const bf16_t* __restrict__ WT,
                                                  const float* __restrict__ bias,
                                                  const float* __restrict__ resid,
                                                  float* __restrict__ outp) {
    int lane = threadIdx.x & 63;
    int w    = threadIdx.x >> 6;
    int lrow = lane & 15, quad = lane >> 4;
    int mbase = blockIdx.x * 64 + (w & 1) * 32;
    int nbase = blockIdx.y * 64 + (w >> 1) * 32;

    f32x4 acc[2][2] = {};
    const bf16_t* a0p = A  + (size_t)(mbase + lrow) * C512 + quad * 8;
    const bf16_t* a1p = a0p + 16 * C512;
    const bf16_t* b0p = WT + (size_t)(nbase + lrow) * C512 + quad * 8;
    const bf16_t* b1p = b0p + 16 * C512;

    #pragma unroll 4
    for (int kk = 0; kk < 16; kk++) {
        bf16x8 a0 = ld8(a0p + kk * 32);
        bf16x8 a1 = ld8(a1p + kk * 32);
        bf16x8 b0 = ld8(b0p + kk * 32);
        bf16x8 b1 = ld8(b1p + kk * 32);
        acc[0][0] = mfma16(a0, b0, acc[0][0]);
        acc[0][1] = mfma16(a0, b1, acc[0][1]);
        acc[1][0] = mfma16(a1, b0, acc[1][0]);
        acc[1][1] = mfma16(a1, b1, acc[1][1]);
    }

    #pragma unroll
    for (int mi = 0; mi < 2; mi++) {
        #pragma unroll
        for (int ni = 0; ni < 2; ni++) {
            int col = nbase + ni * 16 + lrow;
            float bvv = bias[col];
            int rowb = mbase + mi * 16 + quad * 4;
            #pragma unroll
            for (int i = 0; i < 4; i++) {
                size_t idx = (size_t)(rowb + i) * C512 + col;
                outp[idx] = acc[mi][ni][i] + bvv + resid[idx];
            }
        }
    }
}

// ---------------- flash attention v4 (Q-tile 128, split-K x4) ---------------
// Grid 256 blocks = 8 XCD-groups (batch x 4 splits) x 32 Q-tiles.
// Block = 1024 thr, 16 waves: rg = w>>1 (16 q-rows), half = w&1 (256 chs).
// K staged in LDS (fragment-major, dbuf, 64 KB); V direct from global VT
// (8 same-half waves re-read the 16 KB tile -> L1 absorbs).
// Output: unnormalized acc (bf16) + per-row (m,l) for the combine pass.
__global__ __launch_bounds__(1024, 4) void attn_k(const bf16_t* __restrict__ Q,
                                                  const bf16_t* __restrict__ K,
                                                  const bf16_t* __restrict__ VT,
                                                  bf16_t* __restrict__ Op0,
                                                  bf16_t* __restrict__ Op1,
                                                  bf16_t* __restrict__ Op2,
                                                  bf16_t* __restrict__ Op3,
                                                  float2* __restrict__ ml) {
    __shared__ bf16_t kbuf[2 * 16384];   // 64 KB: K-tile dbuf
    __shared__ bf16_t pbuf[16 * 640];    // 20 KB: per-wave P, row stride 40

    int lane = threadIdx.x & 63;
    int w    = threadIdx.x >> 6;         // 0..15
    int rg   = w >> 1, half = w & 1;
    int lrow = lane & 15, quad = lane >> 4;

    // XCD swizzle: xcd = blockIdx.x & 7 == (b, sp); slot = q-tile.
    int xcd  = blockIdx.x & 7;
    int qt   = blockIdx.x >> 3;          // 0..31
    int b  = xcd >> 2;
    int sp = xcd & 3;

    size_t qbase = (size_t)b * SEQ + qt * 128;
    const bf16_t* Kb = K + ((size_t)b * SEQ + sp * 1024) * C512;
    const bf16_t* Vg = VT + ((size_t)(b * C512 + half * 256 + lrow)) * SEQ
                          + sp * 1024 + quad * 8;
    bf16_t* pw = pbuf + w * 640;

    // Q fragments for this wave's 16 rows (QSCALE folded into wq/bq)
    bf16x8 qf[16];
    {
        const bf16_t* qp = Q + (qbase + rg * 16 + lrow) * C512 + quad * 8;
        #pragma unroll
        for (int kk = 0; kk < 16; kk++) qf[kk] = ld8(qp + kk * 32);
    }

    // stage K-tile kt into dbuf half `buf` (fragment-major; 2 chunks/wave)
    auto stageK = [&](int buf, int kt) {
        bf16_t* kd = kbuf + buf * 16384;
        #pragma unroll
        for (int ii = 0; ii < 2; ii++) {
            int i = w * 2 + ii;                      // chunk-instr 0..31
            int kk = i >> 1, nt = i & 1;
            const bf16_t* gp = Kb + (size_t)(kt * 32 + nt * 16 + lrow) * C512
                                  + kk * 32 + quad * 8;
            gload16(gp, kd + i * 512);
        }
    };

    f32x4 acc[16] = {};                  // 16 rows x 256 chs (unnormalized)
    float mst[4] = {-1e30f, -1e30f, -1e30f, -1e30f};
    float lst[4] = {0.f, 0.f, 0.f, 0.f};
    bf16x8 onesf;
    #pragma unroll
    for (int j = 0; j < 8; j++) onesf[j] = (bf16_t)1.0f;

    stageK(0, 0);

    for (int kt = 0; kt < KTILES; kt++) {
        int cur = kt & 1;
        __syncthreads();                 // stage(kt) complete; prev reads done
        if (kt + 1 < KTILES) stageK(1 - cur, kt + 1);   // overlaps compute

        const bf16_t* kl = kbuf + cur * 16384;

        // ---- S = Q K^T (16 rows x 32 keys) ----
        f32x4 s0 = {}, s1 = {};
        #pragma unroll
        for (int kk = 0; kk < 16; kk++) {
            s0 = mfma16(qf[kk], ld8(kl + (kk * 2 + 0) * 512 + lane * 8), s0);
            s1 = mfma16(qf[kk], ld8(kl + (kk * 2 + 1) * 512 + lane * 8), s1);
        }

        // ---- online softmax: max via shuffles, sum via ones-MFMA below ----
        float p0[4], p1[4], alpha[4];
        #pragma unroll
        for (int i = 0; i < 4; i++) {
            float v0 = s0[i], v1 = s1[i];
            float mx = fmaxf(v0, v1);
            #pragma unroll
            for (int d = 8; d >= 1; d >>= 1) mx = fmaxf(mx, __shfl_xor(mx, d));
            float mnew = fmaxf(mst[i], mx);
            alpha[i] = __expf(mst[i] - mnew);
            p0[i] = __expf(v0 - mnew);
            p1[i] = __expf(v1 - mnew);
            mst[i] = mnew;
        }
        // rescale acc only if some row's max moved (exact: alpha==1 else)
        float am = fminf(fminf(alpha[0], alpha[1]), fminf(alpha[2], alpha[3]));
        if (__any(am < 1.0f)) {
            #pragma unroll
            for (int n = 0; n < 16; n++)
                #pragma unroll
                for (int i = 0; i < 4; i++) acc[n][i] *= alpha[i];
        }

        // ---- P: C-layout -> A-layout via wave-private LDS (stride 40) ----
        #pragma unroll
        for (int i = 0; i < 4; i++) {
            pw[(quad * 4 + i) * 40 + lrow]      = (bf16_t)p0[i];
            pw[(quad * 4 + i) * 40 + 16 + lrow] = (bf16_t)p1[i];
        }
        bf16x8 pf = ld8(pw + lrow * 40 + quad * 8);

        // row-sums of P via ones-MFMA (replaces 16 shuffle ops)
        f32x4 lz = {};
        f32x4 lrs = mfma16(pf, onesf, lz);

        // ---- O += P V, V direct from global (lane-contiguous ld8) ----
        const bf16_t* vp = Vg + kt * 32;
        #pragma unroll
        for (int nv = 0; nv < 16; nv++)
            acc[nv] = mfma16(pf, ld8(vp + (size_t)nv * 16 * SEQ), acc[nv]);

        #pragma unroll
        for (int i = 0; i < 4; i++) lst[i] = lst[i] * alpha[i] + lrs[i];
    }

    // ---- store unnormalized partial + (m,l) ----
    bf16_t* Ops = (sp == 0) ? Op0 : (sp == 1) ? Op1 : (sp == 2) ? Op2 : Op3;
    bf16_t* op = Ops + (qbase + rg * 16) * C512;
    #pragma unroll
    for (int nv = 0; nv < 16; nv++) {
        int c = half * 256 + nv * 16 + lrow;
        #pragma unroll
        for (int i = 0; i < 4; i++)
            op[(size_t)(quad * 4 + i) * C512 + c] = (bf16_t)acc[nv][i];
    }
    if (half == 0 && lrow == 0) {
        #pragma unroll
        for (int i = 0; i < 4; i++)
            ml[(size_t)sp * NPIX + qbase + rg * 16 + quad * 4 + i] =
                make_float2(mst[i], lst[i]);
    }
}

// ---------------- combine the four split-K partials -------------------------
__global__ __launch_bounds__(256) void attn_combine_k(const bf16_t* __restrict__ Op0,
                                                      const bf16_t* __restrict__ Op1,
                                                      const bf16_t* __restrict__ Op2,
                                                      const bf16_t* __restrict__ Op3,
                                                      const float2* __restrict__ ml,
                                                      bf16_t* __restrict__ O) {
    int idx = blockIdx.x * 256 + threadIdx.x;    // 524288 threads
    int row = idx >> 6;
    int c8  = (idx & 63) << 3;
    float2 s0 = ml[row],            s1 = ml[NPIX + row];
    float2 s2 = ml[2 * NPIX + row], s3 = ml[3 * NPIX + row];
    float m = fmaxf(fmaxf(s0.x, s1.x), fmaxf(s2.x, s3.x));
    float a0 = __expf(s0.x - m), a1 = __expf(s1.x - m);
    float a2 = __expf(s2.x - m), a3 = __expf(s3.x - m);
    float inv = 1.0f / (a0 * s0.y + a1 * s1.y + a2 * s2.y + a3 * s3.y);
    a0 *= inv; a1 *= inv; a2 *= inv; a3 *= inv;
    size_t base = (size_t)row * C512 + c8;
    bf16x8 o0 = ld8(Op0 + base), o1 = ld8(Op1 + base);
    bf16x8 o2 = ld8(Op2 + base), o3 = ld8(Op3 + base);
    bf16x8 o;
    #pragma unroll
    for (int j = 0; j < 8; j++)
        o[j] = (bf16_t)(a0 * (float)o0[j] + a1 * (float)o1[j] +
                        a2 * (float)o2[j] + a3 * (float)o3[j]);
    *reinterpret_cast<bf16x8*>(O + base) = o;
}

// ---------------------------------------------------------------------------
extern "C" void kernel_launch(void* const* d_in, const int* in_sizes, int n_in,
                              void* d_out, int out_size, void* d_ws, size_t ws_size,
                              hipStream_t stream) {
    const float* x     = (const float*)d_in[0];
    const float* gamma = (const float*)d_in[1];
    const float* beta  = (const float*)d_in[2];
    const float* wq = (const float*)d_in[3];  const float* bq = (const float*)d_in[4];
    const float* wk = (const float*)d_in[5];  const float* bk = (const float*)d_in[6];
    const float* wv = (const float*)d_in[7];  const float* bv = (const float*)d_in[8];
    const float* wp = (const float*)d_in[9];  const float* bp = (const float*)d_in[10];
    float* out = (float*)d_out;

    char* ws = (char*)d_ws;
    size_t off = 0;
    float*  stats  = (float*)(ws + off);   off += 1024;
    bf16_t* xn     = (bf16_t*)(ws + off);  off += (size_t)NPIX * C512 * 2;  // later Op0
    bf16_t* wqkvT  = (bf16_t*)(ws + off);  off += (size_t)3 * C512 * C512 * 2;
    bf16_t* wpT    = (bf16_t*)(ws + off);  off += (size_t)C512 * C512 * 2;
    bf16_t* Qb     = (bf16_t*)(ws + off);  off += (size_t)NPIX * C512 * 2;  // later Ob
    bf16_t* Kb     = (bf16_t*)(ws + off);  off += (size_t)NPIX * C512 * 2;
    bf16_t* VTb    = (bf16_t*)(ws + off);  off += (size_t)NPIX * C512 * 2;
    bf16_t* Op1    = (bf16_t*)(ws + off);  off += (size_t)NPIX * C512 * 2;
    bf16_t* Op2    = (bf16_t*)(ws + off);  off += (size_t)NPIX * C512 * 2;
    bf16_t* Op3    = (bf16_t*)(ws + off);  off += (size_t)NPIX * C512 * 2;
    float2* ml     = (float2*)(ws + off);  off += (size_t)NSPLIT * NPIX * sizeof(float2);
    bf16_t* Op0 = xn;     // xn is dead after gemm_qkv_k
    bf16_t* Ob  = Qb;     // Q is dead after attn_k

    gn_stats_k<<<64, 256, 0, stream>>>(x, stats);
    wt_conv_k<<<dim3(1024, 4), 256, 0, stream>>>(wq, wk, wv, wp, wqkvT, wpT);
    xn_k<<<4096, 256, 0, stream>>>(x, stats, gamma, beta, xn);

    gemm_qkv_k<<<dim3(128, 24), 256, 0, stream>>>(xn, wqkvT, bq, bk, bv, Qb, Kb, VTb);

    attn_k<<<256, 1024, 0, stream>>>(Qb, Kb, VTb, Op0, Op1, Op2, Op3, ml);
    attn_combine_k<<<2048, 256, 0, stream>>>(Op0, Op1, Op2, Op3, ml, Ob);

    gemm_out_k<<<dim3(128, 8), 256, 0, stream>>>(Ob, wpT, bp, x, out);
}

// Round 5
// 601.431 us; speedup vs baseline: 1.7922x; 1.7922x over previous
//
#include <hip/hip_runtime.h>

// ---------------------------------------------------------------------------
// AttentionBlock: GroupNorm(32) -> q,k,v = xn@W+b -> softmax(q k^T / sqrt(C)) v
//                 -> out@wp+bp + x.   B=2, H=W=64, C=512, S=4096 per batch.
// Round 5: round-4's Q-tile-128 regressed purely via VGPR collapse
//   (__launch_bounds__(1024,4) -> 64 VGPR cap -> acc+qf spilled -> 2.9 GB
//   scratch traffic). Same amortization idea within the register budget:
//   - block = 512 thr (8 waves = 4 rowgroups x 2 halves), Q-tile 64.
//   - split-K x4 -> 512 blocks, 2 blocks/CU (74 KB LDS), 16 waves/CU.
//   - __launch_bounds__(512,2): VGPR cap 128 under BOTH launch-bounds
//     interpretations (CUDA min-blocks: 16 waves/CU -> 2048/16 = 128;
//     waves/EU: 512/2 = 256). Inner loop identical to round 3 (known-good
//     128-reg allocation).
// ---------------------------------------------------------------------------

typedef __bf16 bf16_t;
typedef __bf16 bf16x8 __attribute__((ext_vector_type(8)));
typedef __bf16 bf16x4 __attribute__((ext_vector_type(4)));
typedef float  f32x4  __attribute__((ext_vector_type(4)));

__device__ __forceinline__ bf16x8 ld8(const bf16_t* p) {
    return *reinterpret_cast<const bf16x8*>(p);
}
__device__ __forceinline__ f32x4 mfma16(bf16x8 a, bf16x8 b, f32x4 c) {
    return __builtin_amdgcn_mfma_f32_16x16x32_bf16(a, b, c, 0, 0, 0);
}
__device__ __forceinline__ void gload16(const bf16_t* gp, bf16_t* lp) {
    // HW semantics: LDS dest = uniform base + laneid*16B; gp is per-lane.
    __builtin_amdgcn_global_load_lds(
        (const __attribute__((address_space(1))) void*)gp,
        (__attribute__((address_space(3))) void*)lp, 16, 0, 0);
}

#define NPIX 8192      // B*H*W
#define C512 512
#define SEQ  4096      // H*W per batch
#define QSCALE 0.044194173824159216f   // 512^-0.5
#define NSPLIT 4
#define KTILES 32      // 32-key tiles per split (1024 keys per split)

// ---------------- GroupNorm stats: one block per (b,g), 64 blocks -----------
__global__ __launch_bounds__(256) void gn_stats_k(const float* __restrict__ x,
                                                  float* __restrict__ stats) {
    int bg = blockIdx.x;               // b*32+g
    int b  = bg >> 5, g = bg & 31;
    const float* xp = x + (size_t)b * SEQ * C512 + g * 16;
    float s = 0.f, s2 = 0.f;
    for (int p = threadIdx.x; p < SEQ; p += 256) {
        const float4* q = reinterpret_cast<const float4*>(xp + (size_t)p * C512);
        #pragma unroll
        for (int i = 0; i < 4; i++) {
            float4 v = q[i];
            s  += v.x + v.y + v.z + v.w;
            s2 += v.x*v.x + v.y*v.y + v.z*v.z + v.w*v.w;
        }
    }
    #pragma unroll
    for (int off = 32; off >= 1; off >>= 1) {
        s  += __shfl_down(s, off);
        s2 += __shfl_down(s2, off);
    }
    __shared__ float rs[4], rs2[4];
    int wave = threadIdx.x >> 6;
    if ((threadIdx.x & 63) == 0) { rs[wave] = s; rs2[wave] = s2; }
    __syncthreads();
    if (threadIdx.x == 0) {
        float S = 0.f, S2 = 0.f;
        for (int i = 0; i < 4; i++) { S += rs[i]; S2 += rs2[i]; }
        float mean = S * (1.f / 65536.f);
        float var  = S2 * (1.f / 65536.f) - mean * mean;
        stats[bg * 2]     = mean;
        stats[bg * 2 + 1] = rsqrtf(var + 1e-5f);
    }
}

// ---------------- weights: fp32 (k,n) -> bf16 transposed (n,k) --------------
// y=0..2 -> wqkvT rows [y*512, y*512+512); y=0 (wq) folded with QSCALE.
// y=3 -> wpT.
__global__ __launch_bounds__(256) void wt_conv_k(const float* wq, const float* wk,
                                                 const float* wv, const float* wp,
                                                 bf16_t* wqkvT, bf16_t* wpT) {
    int y = blockIdx.y;
    const float* w = (y == 0) ? wq : (y == 1) ? wk : (y == 2) ? wv : wp;
    float scale = (y == 0) ? QSCALE : 1.0f;
    int tid = blockIdx.x * 256 + threadIdx.x;     // 262144 total
    int n = tid >> 9, k = tid & 511;
    bf16_t val = (bf16_t)(w[(size_t)k * C512 + n] * scale);
    if (y < 3) wqkvT[((size_t)y * C512 + n) * C512 + k] = val;
    else       wpT[(size_t)n * C512 + k] = val;
}

// ---------------- xn = groupnorm(x)*gamma+beta -> bf16 ----------------------
__global__ __launch_bounds__(256) void xn_k(const float* __restrict__ x,
                                            const float* __restrict__ stats,
                                            const float* __restrict__ gamma,
                                            const float* __restrict__ beta,
                                            bf16_t* __restrict__ xn) {
    size_t idx = ((size_t)blockIdx.x * 256 + threadIdx.x) * 4;   // elem index
    int c = (int)(idx & 511);
    size_t pix = idx >> 9;
    int b = (int)(pix >> 12);
    int g = c >> 4;
    float mean = stats[(b * 32 + g) * 2];
    float rstd = stats[(b * 32 + g) * 2 + 1];
    float4 v  = *reinterpret_cast<const float4*>(x + idx);
    float4 gm = *reinterpret_cast<const float4*>(gamma + c);
    float4 bt = *reinterpret_cast<const float4*>(beta + c);
    bf16x4 o;
    o[0] = (bf16_t)((v.x - mean) * rstd * gm.x + bt.x);
    o[1] = (bf16_t)((v.y - mean) * rstd * gm.y + bt.y);
    o[2] = (bf16_t)((v.z - mean) * rstd * gm.z + bt.z);
    o[3] = (bf16_t)((v.w - mean) * rstd * gm.w + bt.w);
    *reinterpret_cast<bf16x4*>(xn + idx) = o;
}

// ---------------- fused QKV GEMM: D(8192,1536) = xn x wqkvT^T + bias --------
__global__ __launch_bounds__(256) void gemm_qkv_k(const bf16_t* __restrict__ A,
                                                  const bf16_t* __restrict__ WT,
                                                  const float* __restrict__ bq,
                                                  const float* __restrict__ bk,
                                                  const float* __restrict__ bv,
                                                  bf16_t* __restrict__ Qb,
                                                  bf16_t* __restrict__ Kb,
                                                  bf16_t* __restrict__ VTb) {
    int lane = threadIdx.x & 63;
    int w    = threadIdx.x >> 6;          // 4 waves, 2x2
    int lrow = lane & 15, quad = lane >> 4;
    int mbase = blockIdx.x * 64 + (w & 1) * 32;
    int nbase = blockIdx.y * 64 + (w >> 1) * 32;

    f32x4 acc[2][2] = {};
    const bf16_t* a0p = A  + (size_t)(mbase + lrow) * C512 + quad * 8;
    const bf16_t* a1p = a0p + 16 * C512;
    const bf16_t* b0p = WT + (size_t)(nbase + lrow) * C512 + quad * 8;
    const bf16_t* b1p = b0p + 16 * C512;

    #pragma unroll 4
    for (int kk = 0; kk < 16; kk++) {
        bf16x8 a0 = ld8(a0p + kk * 32);
        bf16x8 a1 = ld8(a1p + kk * 32);
        bf16x8 b0 = ld8(b0p + kk * 32);
        bf16x8 b1 = ld8(b1p + kk * 32);
        acc[0][0] = mfma16(a0, b0, acc[0][0]);
        acc[0][1] = mfma16(a0, b1, acc[0][1]);
        acc[1][0] = mfma16(a1, b0, acc[1][0]);
        acc[1][1] = mfma16(a1, b1, acc[1][1]);
    }

    #pragma unroll
    for (int mi = 0; mi < 2; mi++) {
        #pragma unroll
        for (int ni = 0; ni < 2; ni++) {
            int colG = nbase + ni * 16 + lrow;
            int seg = colG >> 9, col = colG & 511;
            const float* bias = (seg == 0) ? bq : (seg == 1) ? bk : bv;
            float bvv = bias[col] * ((seg == 0) ? QSCALE : 1.0f);
            int rowb = mbase + mi * 16 + quad * 4;
            #pragma unroll
            for (int i = 0; i < 4; i++) {
                int row = rowb + i;
                bf16_t val = (bf16_t)(acc[mi][ni][i] + bvv);
                if (seg == 0) {
                    Qb[(size_t)row * C512 + col] = val;
                } else if (seg == 1) {
                    Kb[(size_t)row * C512 + col] = val;
                } else {
                    int b = row >> 12, s = row & 4095;
                    VTb[((size_t)(b * C512 + col)) * SEQ + s] = val;
                }
            }
        }
    }
}

// ---------------- out-projection GEMM + residual ----------------------------
__global__ __launch_bounds__(256) void gemm_out_k(const bf16_t* __restrict__ A,
                                                  const bf16_t* __restrict__ WT,
                                                  const float* __restrict__ bias,
                                                  const float* __restrict__ resid,
                                                  float* __restrict__ outp) {
    int lane = threadIdx.x & 63;
    int w    = threadIdx.x >> 6;
    int lrow = lane & 15, quad = lane >> 4;
    int mbase = blockIdx.x * 64 + (w & 1) * 32;
    int nbase = blockIdx.y * 64 + (w >> 1) * 32;

    f32x4 acc[2][2] = {};
    const bf16_t* a0p = A  + (size_t)(mbase + lrow) * C512 + quad * 8;
    const bf16_t* a1p = a0p + 16 * C512;
    const bf16_t* b0p = WT + (size_t)(nbase + lrow) * C512 + quad * 8;
    const bf16_t* b1p = b0p + 16 * C512;

    #pragma unroll 4
    for (int kk = 0; kk < 16; kk++) {
        bf16x8 a0 = ld8(a0p + kk * 32);
        bf16x8 a1 = ld8(a1p + kk * 32);
        bf16x8 b0 = ld8(b0p + kk * 32);
        bf16x8 b1 = ld8(b1p + kk * 32);
        acc[0][0] = mfma16(a0, b0, acc[0][0]);
        acc[0][1] = mfma16(a0, b1, acc[0][1]);
        acc[1][0] = mfma16(a1, b0, acc[1][0]);
        acc[1][1] = mfma16(a1, b1, acc[1][1]);
    }

    #pragma unroll
    for (int mi = 0; mi < 2; mi++) {
        #pragma unroll
        for (int ni = 0; ni < 2; ni++) {
            int col = nbase + ni * 16 + lrow;
            float bvv = bias[col];
            int rowb = mbase + mi * 16 + quad * 4;
            #pragma unroll
            for (int i = 0; i < 4; i++) {
                size_t idx = (size_t)(rowb + i) * C512 + col;
                outp[idx] = acc[mi][ni][i] + bvv + resid[idx];
            }
        }
    }
}

// ---------------- flash attention v5 (Q-tile 64, split-K x4) ----------------
// Grid 512 blocks = 8 XCD-groups (batch x 4 splits) x 64 Q-tiles.
// Block = 512 thr, 8 waves: rg = w>>1 (16 q-rows), half = w&1 (256 chs).
// K staged in LDS (fragment-major, dbuf, 64 KB); V direct from global VT.
// Output: unnormalized acc (bf16) + per-row (m,l) for the combine pass.
__global__ __launch_bounds__(512, 2) void attn_k(const bf16_t* __restrict__ Q,
                                                 const bf16_t* __restrict__ K,
                                                 const bf16_t* __restrict__ VT,
                                                 bf16_t* __restrict__ Op0,
                                                 bf16_t* __restrict__ Op1,
                                                 bf16_t* __restrict__ Op2,
                                                 bf16_t* __restrict__ Op3,
                                                 float2* __restrict__ ml) {
    __shared__ bf16_t kbuf[2 * 16384];   // 64 KB: K-tile dbuf
    __shared__ bf16_t pbuf[8 * 640];     // 10 KB: per-wave P, row stride 40

    int lane = threadIdx.x & 63;
    int w    = threadIdx.x >> 6;         // 0..7
    int rg   = w >> 1, half = w & 1;
    int lrow = lane & 15, quad = lane >> 4;

    // XCD swizzle: xcd = blockIdx.x & 7 == (b, sp); rest = q-tile.
    int xcd  = blockIdx.x & 7;
    int qt   = blockIdx.x >> 3;          // 0..63
    int b  = xcd >> 2;
    int sp = xcd & 3;

    size_t qbase = (size_t)b * SEQ + qt * 64;
    const bf16_t* Kb = K + ((size_t)b * SEQ + sp * 1024) * C512;
    const bf16_t* Vg = VT + ((size_t)(b * C512 + half * 256 + lrow)) * SEQ
                          + sp * 1024 + quad * 8;
    bf16_t* pw = pbuf + w * 640;

    // Q fragments for this wave's 16 rows (QSCALE folded into wq/bq)
    bf16x8 qf[16];
    {
        const bf16_t* qp = Q + (qbase + rg * 16 + lrow) * C512 + quad * 8;
        #pragma unroll
        for (int kk = 0; kk < 16; kk++) qf[kk] = ld8(qp + kk * 32);
    }

    // stage K-tile kt into dbuf half `buf` (fragment-major; 4 chunks/wave)
    auto stageK = [&](int buf, int kt) {
        bf16_t* kd = kbuf + buf * 16384;
        #pragma unroll
        for (int ii = 0; ii < 4; ii++) {
            int i = w * 4 + ii;                      // chunk-instr 0..31
            int kk = i >> 1, nt = i & 1;
            const bf16_t* gp = Kb + (size_t)(kt * 32 + nt * 16 + lrow) * C512
                                  + kk * 32 + quad * 8;
            gload16(gp, kd + i * 512);
        }
    };

    f32x4 acc[16] = {};                  // 16 rows x 256 chs (unnormalized)
    float mst[4] = {-1e30f, -1e30f, -1e30f, -1e30f};
    float lst[4] = {0.f, 0.f, 0.f, 0.f};
    bf16x8 onesf;
    #pragma unroll
    for (int j = 0; j < 8; j++) onesf[j] = (bf16_t)1.0f;

    stageK(0, 0);

    for (int kt = 0; kt < KTILES; kt++) {
        int cur = kt & 1;
        __syncthreads();                 // stage(kt) complete; prev reads done
        if (kt + 1 < KTILES) stageK(1 - cur, kt + 1);   // overlaps compute

        const bf16_t* kl = kbuf + cur * 16384;

        // ---- S = Q K^T (16 rows x 32 keys) ----
        f32x4 s0 = {}, s1 = {};
        #pragma unroll
        for (int kk = 0; kk < 16; kk++) {
            s0 = mfma16(qf[kk], ld8(kl + (kk * 2 + 0) * 512 + lane * 8), s0);
            s1 = mfma16(qf[kk], ld8(kl + (kk * 2 + 1) * 512 + lane * 8), s1);
        }

        // ---- online softmax: max via shuffles, sum via ones-MFMA below ----
        float p0[4], p1[4], alpha[4];
        #pragma unroll
        for (int i = 0; i < 4; i++) {
            float v0 = s0[i], v1 = s1[i];
            float mx = fmaxf(v0, v1);
            #pragma unroll
            for (int d = 8; d >= 1; d >>= 1) mx = fmaxf(mx, __shfl_xor(mx, d));
            float mnew = fmaxf(mst[i], mx);
            alpha[i] = __expf(mst[i] - mnew);
            p0[i] = __expf(v0 - mnew);
            p1[i] = __expf(v1 - mnew);
            mst[i] = mnew;
        }
        // rescale acc only if some row's max moved (exact: alpha==1 else)
        float am = fminf(fminf(alpha[0], alpha[1]), fminf(alpha[2], alpha[3]));
        if (__any(am < 1.0f)) {
            #pragma unroll
            for (int n = 0; n < 16; n++)
                #pragma unroll
                for (int i = 0; i < 4; i++) acc[n][i] *= alpha[i];
        }

        // ---- P: C-layout -> A-layout via wave-private LDS (stride 40) ----
        #pragma unroll
        for (int i = 0; i < 4; i++) {
            pw[(quad * 4 + i) * 40 + lrow]      = (bf16_t)p0[i];
            pw[(quad * 4 + i) * 40 + 16 + lrow] = (bf16_t)p1[i];
        }
        bf16x8 pf = ld8(pw + lrow * 40 + quad * 8);

        // row-sums of P via ones-MFMA (replaces 16 shuffle ops)
        f32x4 lz = {};
        f32x4 lrs = mfma16(pf, onesf, lz);

        // ---- O += P V, V direct from global (lane-contiguous ld8) ----
        const bf16_t* vp = Vg + kt * 32;
        #pragma unroll
        for (int nv = 0; nv < 16; nv++)
            acc[nv] = mfma16(pf, ld8(vp + (size_t)nv * 16 * SEQ), acc[nv]);

        #pragma unroll
        for (int i = 0; i < 4; i++) lst[i] = lst[i] * alpha[i] + lrs[i];
    }

    // ---- store unnormalized partial + (m,l) ----
    bf16_t* Ops = (sp == 0) ? Op0 : (sp == 1) ? Op1 : (sp == 2) ? Op2 : Op3;
    bf16_t* op = Ops + (qbase + rg * 16) * C512;
    #pragma unroll
    for (int nv = 0; nv < 16; nv++) {
        int c = half * 256 + nv * 16 + lrow;
        #pragma unroll
        for (int i = 0; i < 4; i++)
            op[(size_t)(quad * 4 + i) * C512 + c] = (bf16_t)acc[nv][i];
    }
    if (half == 0 && lrow == 0) {
        #pragma unroll
        for (int i = 0; i < 4; i++)
            ml[(size_t)sp * NPIX + qbase + rg * 16 + quad * 4 + i] =
                make_float2(mst[i], lst[i]);
    }
}

// ---------------- combine the four split-K partials -------------------------
__global__ __launch_bounds__(256) void attn_combine_k(const bf16_t* __restrict__ Op0,
                                                      const bf16_t* __restrict__ Op1,
                                                      const bf16_t* __restrict__ Op2,
                                                      const bf16_t* __restrict__ Op3,
                                                      const float2* __restrict__ ml,
                                                      bf16_t* __restrict__ O) {
    int idx = blockIdx.x * 256 + threadIdx.x;    // 524288 threads
    int row = idx >> 6;
    int c8  = (idx & 63) << 3;
    float2 s0 = ml[row],            s1 = ml[NPIX + row];
    float2 s2 = ml[2 * NPIX + row], s3 = ml[3 * NPIX + row];
    float m = fmaxf(fmaxf(s0.x, s1.x), fmaxf(s2.x, s3.x));
    float a0 = __expf(s0.x - m), a1 = __expf(s1.x - m);
    float a2 = __expf(s2.x - m), a3 = __expf(s3.x - m);
    float inv = 1.0f / (a0 * s0.y + a1 * s1.y + a2 * s2.y + a3 * s3.y);
    a0 *= inv; a1 *= inv; a2 *= inv; a3 *= inv;
    size_t base = (size_t)row * C512 + c8;
    bf16x8 o0 = ld8(Op0 + base), o1 = ld8(Op1 + base);
    bf16x8 o2 = ld8(Op2 + base), o3 = ld8(Op3 + base);
    bf16x8 o;
    #pragma unroll
    for (int j = 0; j < 8; j++)
        o[j] = (bf16_t)(a0 * (float)o0[j] + a1 * (float)o1[j] +
                        a2 * (float)o2[j] + a3 * (float)o3[j]);
    *reinterpret_cast<bf16x8*>(O + base) = o;
}

// ---------------------------------------------------------------------------
extern "C" void kernel_launch(void* const* d_in, const int* in_sizes, int n_in,
                              void* d_out, int out_size, void* d_ws, size_t ws_size,
                              hipStream_t stream) {
    const float* x     = (const float*)d_in[0];
    const float* gamma = (const float*)d_in[1];
    const float* beta  = (const float*)d_in[2];
    const float* wq = (const float*)d_in[3];  const float* bq = (const float*)d_in[4];
    const float* wk = (const float*)d_in[5];  const float* bk = (const float*)d_in[6];
    const float* wv = (const float*)d_in[7];  const float* bv = (const float*)d_in[8];
    const float* wp = (const float*)d_in[9];  const float* bp = (const float*)d_in[10];
    float* out = (float*)d_out;

    char* ws = (char*)d_ws;
    size_t off = 0;
    float*  stats  = (float*)(ws + off);   off += 1024;
    bf16_t* xn     = (bf16_t*)(ws + off);  off += (size_t)NPIX * C512 * 2;  // later Op0
    bf16_t* wqkvT  = (bf16_t*)(ws + off);  off += (size_t)3 * C512 * C512 * 2;
    bf16_t* wpT    = (bf16_t*)(ws + off);  off += (size_t)C512 * C512 * 2;
    bf16_t* Qb     = (bf16_t*)(ws + off);  off += (size_t)NPIX * C512 * 2;  // later Ob
    bf16_t* Kb     = (bf16_t*)(ws + off);  off += (size_t)NPIX * C512 * 2;
    bf16_t* VTb    = (bf16_t*)(ws + off);  off += (size_t)NPIX * C512 * 2;
    bf16_t* Op1    = (bf16_t*)(ws + off);  off += (size_t)NPIX * C512 * 2;
    bf16_t* Op2    = (bf16_t*)(ws + off);  off += (size_t)NPIX * C512 * 2;
    bf16_t* Op3    = (bf16_t*)(ws + off);  off += (size_t)NPIX * C512 * 2;
    float2* ml     = (float2*)(ws + off);  off += (size_t)NSPLIT * NPIX * sizeof(float2);
    bf16_t* Op0 = xn;     // xn is dead after gemm_qkv_k
    bf16_t* Ob  = Qb;     // Q is dead after attn_k

    gn_stats_k<<<64, 256, 0, stream>>>(x, stats);
    wt_conv_k<<<dim3(1024, 4), 256, 0, stream>>>(wq, wk, wv, wp, wqkvT, wpT);
    xn_k<<<4096, 256, 0, stream>>>(x, stats, gamma, beta, xn);

    gemm_qkv_k<<<dim3(128, 24), 256, 0, stream>>>(xn, wqkvT, bq, bk, bv, Qb, Kb, VTb);

    attn_k<<<512, 512, 0, stream>>>(Qb, Kb, VTb, Op0, Op1, Op2, Op3, ml);
    attn_combine_k<<<2048, 256, 0, stream>>>(Op0, Op1, Op2, Op3, ml, Ob);

    gemm_out_k<<<dim3(128, 8), 256, 0, stream>>>(Ob, wpT, bp, x, out);
}